// Round 8
// baseline (5094.541 us; speedup 1.0000x reference)
//
#include <hip/hip_runtime.h>
#include <hip/hip_bf16.h>
#include <hip/hip_fp16.h>

// ===========================================================================
// CSR build (multi-block scan)
// ===========================================================================
__global__ void hist_kernel(const int* __restrict__ rows, int* __restrict__ counts, int E) {
    int i = blockIdx.x * blockDim.x + threadIdx.x;
    if (i < E) atomicAdd(&counts[rows[i]], 1);
}

// per-256-chunk sums
__global__ void chunk_sum_kernel(const int* __restrict__ counts, int* __restrict__ chunk_sums, int V) {
    __shared__ int sh[256];
    int t = threadIdx.x;
    int i = blockIdx.x * 256 + t;
    sh[t] = (i < V) ? counts[i] : 0;
    __syncthreads();
    for (int st = 128; st > 0; st >>= 1) {
        if (t < st) sh[t] += sh[t + st];
        __syncthreads();
    }
    if (t == 0) chunk_sums[blockIdx.x] = sh[0];
}

// single-block exclusive scan of nchunks (<=256) values, in place
__global__ void scan_chunks_kernel(int* __restrict__ cs, int n) {
    __shared__ int wsum[4];
    int t = threadIdx.x, lane = t & 63, w = t >> 6;
    int orig = (t < n) ? cs[t] : 0;
    int x = orig;
    #pragma unroll
    for (int d = 1; d < 64; d <<= 1) {
        int y = __shfl_up(x, d);
        if (lane >= d) x += y;
    }
    if (lane == 63) wsum[w] = x;
    __syncthreads();
    int wo = 0;
    for (int j = 0; j < w; ++j) wo += wsum[j];
    if (t < n) cs[t] = wo + x - orig;     // exclusive
}

// per-chunk inclusive scan + chunk offset -> row_ptr[i+1]
__global__ void scan_final_kernel(const int* __restrict__ counts, const int* __restrict__ chunk_off,
                                  int* __restrict__ row_ptr, int V) {
    __shared__ int wsum[4];
    int t = threadIdx.x, lane = t & 63, w = t >> 6;
    int i = blockIdx.x * 256 + t;
    int x = (i < V) ? counts[i] : 0;
    #pragma unroll
    for (int d = 1; d < 64; d <<= 1) {
        int y = __shfl_up(x, d);
        if (lane >= d) x += y;
    }
    if (lane == 63) wsum[w] = x;
    __syncthreads();
    int wo = 0;
    for (int j = 0; j < w; ++j) wo += wsum[j];
    if (i < V) row_ptr[i + 1] = chunk_off[blockIdx.x] + wo + x;
    if (i == 0) row_ptr[0] = 0;
}

__global__ void init_cursor_kernel(const int* __restrict__ row_ptr, int* __restrict__ cursor, int V) {
    int i = blockIdx.x * blockDim.x + threadIdx.x;
    if (i < V) cursor[i] = row_ptr[i];
}

__global__ void scatter_kernel(const int* __restrict__ rows, const int* __restrict__ cols,
                               const float* __restrict__ vals, int* __restrict__ cursor,
                               int* __restrict__ cols_s, float* __restrict__ vals_s, int E) {
    int i = blockIdx.x * blockDim.x + threadIdx.x;
    if (i < E) {
        int r = rows[i];
        int p = atomicAdd(&cursor[r], 1);
        cols_s[p] = cols[i];
        vals_s[p] = vals[i];
    }
}

// ===========================================================================
// transpose input (B,16,V) fp32 -> (V, B*16) fp16.  i = v*128 + (b*16+c)
// ===========================================================================
__global__ void transpose_in_kernel(const float* __restrict__ x, __half* __restrict__ X, int V) {
    int total = V * 128;
    for (int i = blockIdx.x * blockDim.x + threadIdx.x; i < total; i += gridDim.x * blockDim.x) {
        int v = i >> 7;
        int t = i & 127;          // t = b*16 + c
        X[i] = __float2half(x[t * V + v]);
    }
}

// ===========================================================================
// SpMM v2 (unchanged from round 7): one wave per node, lane owns VPT half2.
// ===========================================================================
template <int VPT> struct PackT;
template <> struct PackT<1> { using T = float;  };
template <> struct PackT<2> { using T = float2; };
template <> struct PackT<4> { using T = float4; };

template <int VPT>
__global__ __launch_bounds__(256) void spmm2_kernel(
    const int* __restrict__ row_ptr, const int* __restrict__ cols,
    const float* __restrict__ vals, const __half2* __restrict__ src,
    __half2* dst, const __half2* prev, int V) {
    using T = typename PackT<VPT>::T;
    union U { T raw; __half2 h[VPT]; };
    int lane = threadIdx.x & 63;
    int v = (blockIdx.x << 2) | (threadIdx.x >> 6);
    if (v >= V) return;
    const int W = VPT * 64;
    const size_t row = (size_t)v * W + lane * VPT;

    float pr[2 * VPT];
    bool hasp = (prev != nullptr);
    if (hasp) {
        U pv; pv.raw = *(const T*)(prev + row);   // load BEFORE any store
        #pragma unroll
        for (int j = 0; j < VPT; ++j) {
            float2 f = __half22float2(pv.h[j]);
            pr[2 * j] = f.x; pr[2 * j + 1] = f.y;
        }
    }
    float acc[2 * VPT];
    #pragma unroll
    for (int j = 0; j < 2 * VPT; ++j) acc[j] = 0.f;

    int e0 = row_ptr[v], e1 = row_ptr[v + 1];
    int e = e0;
    for (; e + 4 <= e1; e += 4) {
        int   c0 = cols[e],   c1 = cols[e + 1], c2 = cols[e + 2], c3 = cols[e + 3];
        float w0 = vals[e],   w1 = vals[e + 1], w2 = vals[e + 2], w3 = vals[e + 3];
        U g0, g1, g2, g3;
        g0.raw = *(const T*)(src + (size_t)c0 * W + lane * VPT);
        g1.raw = *(const T*)(src + (size_t)c1 * W + lane * VPT);
        g2.raw = *(const T*)(src + (size_t)c2 * W + lane * VPT);
        g3.raw = *(const T*)(src + (size_t)c3 * W + lane * VPT);
        #pragma unroll
        for (int j = 0; j < VPT; ++j) {
            float2 f;
            f = __half22float2(g0.h[j]); acc[2*j] += w0 * f.x; acc[2*j+1] += w0 * f.y;
            f = __half22float2(g1.h[j]); acc[2*j] += w1 * f.x; acc[2*j+1] += w1 * f.y;
            f = __half22float2(g2.h[j]); acc[2*j] += w2 * f.x; acc[2*j+1] += w2 * f.y;
            f = __half22float2(g3.h[j]); acc[2*j] += w3 * f.x; acc[2*j+1] += w3 * f.y;
        }
    }
    for (; e < e1; ++e) {
        int c = cols[e]; float wv = vals[e];
        U g; g.raw = *(const T*)(src + (size_t)c * W + lane * VPT);
        #pragma unroll
        for (int j = 0; j < VPT; ++j) {
            float2 f = __half22float2(g.h[j]);
            acc[2*j] += wv * f.x; acc[2*j+1] += wv * f.y;
        }
    }
    if (hasp) {
        #pragma unroll
        for (int j = 0; j < 2 * VPT; ++j) acc[j] = 2.f * acc[j] - pr[j];
    }
    U o;
    #pragma unroll
    for (int j = 0; j < VPT; ++j) o.h[j] = __floats2half2_rn(acc[2*j], acc[2*j+1]);
    *(T*)(dst + row) = o.raw;
}

// ===========================================================================
// mix v3: LDS-free broadcast GEMM.
// Thread = (node n, batch b). Holds COUT fp32 accumulators in VGPRs.
// W rows are wave-uniform -> s_load broadcast; inner loop = pure v_fmac.
// fin: -1 = write fp32 ACC (+=accum); 0 = relu + fp16 write to resout;
//       1 = + residual (resout old value) + relu + fp16 write to resout.
// ===========================================================================
template <int CIN, int COUT>
__global__ __launch_bounds__(256) void mix3_kernel(
    const __half* __restrict__ in, float* accbuf,
    const float* __restrict__ W, const float* __restrict__ bias,
    __half* resout, int accum, int fin, int V) {
    int g = blockIdx.x * 256 + threadIdx.x;
    int n = g >> 3, b = g & 7;
    if (n >= V) return;
    const __half2* xr = (const __half2*)(in + (size_t)n * 8 * CIN + b * CIN);

    float acc[COUT];
    if (bias) {
        #pragma unroll
        for (int c = 0; c < COUT; ++c) acc[c] = bias[c];
    } else {
        #pragma unroll
        for (int c = 0; c < COUT; ++c) acc[c] = 0.f;
    }
    for (int q = 0; q < CIN / 2; ++q) {
        float2 x = __half22float2(xr[q]);
        const float* w0 = W + (2 * q) * COUT;
        const float* w1 = W + (2 * q + 1) * COUT;
        #pragma unroll
        for (int c = 0; c < COUT; ++c) acc[c] = fmaf(x.x, w0[c], acc[c]);
        #pragma unroll
        for (int c = 0; c < COUT; ++c) acc[c] = fmaf(x.y, w1[c], acc[c]);
    }
    size_t ob = (size_t)n * 8 * COUT + (size_t)b * COUT;
    if (fin < 0) {
        if (accum) {
            #pragma unroll
            for (int c = 0; c < COUT; ++c) acc[c] += accbuf[ob + c];
        }
        #pragma unroll
        for (int c = 0; c < COUT; ++c) accbuf[ob + c] = acc[c];
    } else {
        if (accum) {
            #pragma unroll
            for (int c = 0; c < COUT; ++c) acc[c] += accbuf[ob + c];
        }
        if (fin == 1) {
            #pragma unroll
            for (int c = 0; c < COUT; ++c) acc[c] += __half2float(resout[ob + c]);
        }
        #pragma unroll
        for (int c = 0; c < COUT; ++c) acc[c] = fmaxf(acc[c], 0.f);
        __half2* ro = (__half2*)(resout + ob);    // COUT even in fin modes
        #pragma unroll
        for (int c = 0; c < COUT / 2; ++c)
            ro[c] = __floats2half2_rn(acc[2 * c], acc[2 * c + 1]);
    }
}

// ===========================================================================
// BatchNorm stats over fp16 or fp32 input
// ===========================================================================
__global__ void bn_stats_h_kernel(const __half* __restrict__ x, int C,
                                  float* __restrict__ sums, size_t N) {
    __shared__ float s_sum[256];
    __shared__ float s_sq[256];
    int t = threadIdx.x;
    size_t i0 = (size_t)blockIdx.x * 256 + t;
    size_t step = (size_t)gridDim.x * 256;
    float s = 0.f, q = 0.f;
    for (size_t i = i0; i < N; i += step) {
        float v = __half2float(x[i]);
        s += v; q += v * v;
    }
    s_sum[t] = s; s_sq[t] = q;
    __syncthreads();
    for (int st = 128; st >= C; st >>= 1) {
        if (t < st) { s_sum[t] += s_sum[t + st]; s_sq[t] += s_sq[t + st]; }
        __syncthreads();
    }
    if (t < C) {
        atomicAdd(&sums[t], s_sum[t]);
        atomicAdd(&sums[C + t], s_sq[t]);
    }
}

__global__ void bn_stats_f_kernel(const float* __restrict__ x, int C, int relu_in,
                                  float* __restrict__ sums, size_t N) {
    __shared__ float s_sum[256];
    __shared__ float s_sq[256];
    int t = threadIdx.x;
    size_t i0 = (size_t)blockIdx.x * 256 + t;
    size_t step = (size_t)gridDim.x * 256;
    float s = 0.f, q = 0.f;
    for (size_t i = i0; i < N; i += step) {
        float v = x[i];
        if (relu_in) v = fmaxf(v, 0.f);
        s += v; q += v * v;
    }
    s_sum[t] = s; s_sq[t] = q;
    __syncthreads();
    for (int st = 128; st >= C; st >>= 1) {
        if (t < st) { s_sum[t] += s_sum[t + st]; s_sq[t] += s_sq[t + st]; }
        __syncthreads();
    }
    if (t < C) {
        atomicAdd(&sums[t], s_sum[t]);
        atomicAdd(&sums[C + t], s_sq[t]);
    }
}

__global__ void bn_finalize_kernel(const float* __restrict__ sums, const float* __restrict__ g,
                                   const float* __restrict__ be, float* __restrict__ ss,
                                   int C, float invN) {
    int c = threadIdx.x;
    if (c < C) {
        float m = sums[c] * invN;
        float var = sums[C + c] * invN - m * m;
        float s = g[c] * rsqrtf(var + 1e-5f);
        ss[c] = s;
        ss[C + c] = be[c] - m * s;
    }
}

// in-place affine on fp16 features
__global__ void affine_h_kernel(__half* x, const float* __restrict__ ss, int C, size_t N) {
    size_t stride = (size_t)gridDim.x * blockDim.x;
    for (size_t i = (size_t)blockIdx.x * blockDim.x + threadIdx.x; i < N; i += stride) {
        int c = (int)(i & (size_t)(C - 1));
        x[i] = __float2half(__half2float(x[i]) * ss[c] + ss[C + c]);
    }
}

// y = bn(relu(ACC)) -> fp16
__global__ void affine_f2h_kernel(const float* __restrict__ in, __half* __restrict__ out,
                                  const float* __restrict__ ss, int C, size_t N) {
    size_t stride = (size_t)gridDim.x * blockDim.x;
    for (size_t i = (size_t)blockIdx.x * blockDim.x + threadIdx.x; i < N; i += stride) {
        int c = (int)(i & (size_t)(C - 1));
        float v = fmaxf(in[i], 0.f);
        out[i] = __float2half(v * ss[c] + ss[C + c]);
    }
}

// ===========================================================================
// head: max over nodes of relu(ACC) (m init 0 => implicit relu) + log_softmax
// ===========================================================================
__global__ void maxpool_kernel(const float* __restrict__ x, float* __restrict__ pooled, int V) {
    __shared__ float red[256];
    int o = blockIdx.x;     // 0..79 (b*10+co)
    float m = 0.f;
    for (int v = threadIdx.x; v < V; v += 256)
        m = fmaxf(m, x[(size_t)v * 80 + o]);
    red[threadIdx.x] = m;
    __syncthreads();
    for (int st = 128; st > 0; st >>= 1) {
        if (threadIdx.x < st) red[threadIdx.x] = fmaxf(red[threadIdx.x], red[threadIdx.x + st]);
        __syncthreads();
    }
    if (threadIdx.x == 0) pooled[o] = red[0];
}

// OUTPUT IS FP32 (reference output dtype is float32)
__global__ void lsm_kernel(const float* __restrict__ pooled, float* __restrict__ out) {
    int b = threadIdx.x;
    if (b < 8) {
        float m = -1e30f;
        for (int c = 0; c < 10; ++c) m = fmaxf(m, pooled[b * 10 + c]);
        float s = 0.f;
        for (int c = 0; c < 10; ++c) s += expf(pooled[b * 10 + c] - m);
        float l = logf(s);
        for (int c = 0; c < 10; ++c)
            out[b * 10 + c] = pooled[b * 10 + c] - m - l;
    }
}

// ws too small: report ws_size in MB via absmax (fp32 out)
__global__ void encode_kernel(float* out, float val) {
    int i = threadIdx.x;
    if (i < 80) out[i] = val;
}

// ===========================================================================
// entry
// ===========================================================================
extern "C" void kernel_launch(void* const* d_in, const int* in_sizes, int n_in,
                              void* d_out, int out_size, void* d_ws, size_t ws_size,
                              hipStream_t stream) {
    (void)in_sizes; (void)n_in; (void)out_size;
    const int V = 50000, E = 800000;
    const int NCH = (V + 255) / 256;     // 196 chunks

    auto al = [](size_t x) { return (x + 255) & ~(size_t)255; };
    const size_t ACCB = al((size_t)V * 512 * sizeof(float));      // 102.4 MB
    const size_t FB   = al((size_t)V * 512 * sizeof(__half));     // 51.2 MB
    const size_t need = ACCB + 3 * FB + al((V + 1) * 4) + al(V * 4) + al(E * 4) + al(E * 4)
                      + al(8 * 128 * 4) + al(8 * 128 * 4) + al(80 * 4) + al(NCH * 4);
    if (ws_size < need) {
        encode_kernel<<<1, 128, 0, stream>>>((float*)d_out, (float)(ws_size >> 20));
        return;
    }

    const float* x_in = (const float*)d_in[0];
    const int* rows   = (const int*)d_in[1];
    const int* colsi  = (const int*)d_in[2];
    const float* lvals = (const float*)d_in[3];
    const float* W_in = (const float*)d_in[4];
    const float* b_in = (const float*)d_in[5];
    const float* g1a = (const float*)d_in[6],  *be1a = (const float*)d_in[7];
    const float* W1a = (const float*)d_in[8],  *b1a  = (const float*)d_in[9];
    const float* g1b = (const float*)d_in[10], *be1b = (const float*)d_in[11];
    const float* W1b = (const float*)d_in[12], *b1b  = (const float*)d_in[13];
    const float* g2a = (const float*)d_in[14], *be2a = (const float*)d_in[15];
    const float* W2a = (const float*)d_in[16], *b2a  = (const float*)d_in[17];
    const float* g2b = (const float*)d_in[18], *be2b = (const float*)d_in[19];
    const float* W2b = (const float*)d_in[20], *b2b  = (const float*)d_in[21];
    const float* W2s = (const float*)d_in[22];
    const float* g3a = (const float*)d_in[23], *be3a = (const float*)d_in[24];
    const float* W3a = (const float*)d_in[25], *b3a  = (const float*)d_in[26];
    const float* g3b = (const float*)d_in[27], *be3b = (const float*)d_in[28];
    const float* W3b = (const float*)d_in[29], *b3b  = (const float*)d_in[30];
    const float* g_o = (const float*)d_in[31], *be_o = (const float*)d_in[32];
    const float* W_o = (const float*)d_in[33], *b_o  = (const float*)d_in[34];

    char* wp = (char*)d_ws;
    auto take = [&](size_t bytes) -> void* { void* p = (void*)wp; wp += al(bytes); return p; };
    float*  ACC = (float*)take((size_t)V * 512 * sizeof(float));
    __half* B0  = (__half*)take((size_t)V * 512 * sizeof(__half));
    __half* B1  = (__half*)take((size_t)V * 512 * sizeof(__half));
    __half* B2  = (__half*)take((size_t)V * 512 * sizeof(__half));
    int* row_ptr  = (int*)take((V + 1) * sizeof(int));
    int* cursor   = (int*)take(V * sizeof(int));
    int* cols_s   = (int*)take(E * sizeof(int));
    float* vals_s = (float*)take(E * sizeof(float));
    float* bn_sums = (float*)take(8 * 128 * sizeof(float));
    float* aff     = (float*)take(8 * 128 * sizeof(float));
    float* pooled  = (float*)take(80 * sizeof(float));
    int* chunks    = (int*)take(NCH * sizeof(int));

    // ---- CSR build + input transpose ----
    hipMemsetAsync(cursor, 0, V * sizeof(int), stream);
    hipMemsetAsync(bn_sums, 0, 8 * 128 * sizeof(float), stream);
    hist_kernel<<<(E + 255) / 256, 256, 0, stream>>>(rows, cursor, E);
    chunk_sum_kernel<<<NCH, 256, 0, stream>>>(cursor, chunks, V);
    scan_chunks_kernel<<<1, 256, 0, stream>>>(chunks, NCH);
    scan_final_kernel<<<NCH, 256, 0, stream>>>(cursor, chunks, row_ptr, V);
    init_cursor_kernel<<<(V + 255) / 256, 256, 0, stream>>>(row_ptr, cursor, V);
    scatter_kernel<<<(E + 255) / 256, 256, 0, stream>>>(rows, colsi, lvals, cursor, cols_s, vals_s, E);
    transpose_in_kernel<<<4096, 256, 0, stream>>>(x_in, B0, V);

    // ---- helpers ----
    auto spmm = [&](const __half* src, __half* dst, const __half* prev, int C) {
        int grid = (V + 3) / 4;
        if (C == 16)
            spmm2_kernel<1><<<grid, 256, 0, stream>>>(row_ptr, cols_s, vals_s,
                (const __half2*)src, (__half2*)dst, (const __half2*)prev, V);
        else if (C == 32)
            spmm2_kernel<2><<<grid, 256, 0, stream>>>(row_ptr, cols_s, vals_s,
                (const __half2*)src, (__half2*)dst, (const __half2*)prev, V);
        else
            spmm2_kernel<4><<<grid, 256, 0, stream>>>(row_ptr, cols_s, vals_s,
                (const __half2*)src, (__half2*)dst, (const __half2*)prev, V);
    };
    const int MG = (V * 8 + 255) / 256;
    auto mix = [&](const __half* in, int Cin, int Cout, const float* W,
                   const float* bias, int accum, int fin) {
        if (Cin == 16 && Cout == 32)
            mix3_kernel<16, 32><<<MG, 256, 0, stream>>>(in, ACC, W, bias, B0, accum, fin, V);
        else if (Cin == 32 && Cout == 32)
            mix3_kernel<32, 32><<<MG, 256, 0, stream>>>(in, ACC, W, bias, B0, accum, fin, V);
        else if (Cin == 32 && Cout == 64)
            mix3_kernel<32, 64><<<MG, 256, 0, stream>>>(in, ACC, W, bias, B0, accum, fin, V);
        else if (Cin == 64 && Cout == 64)
            mix3_kernel<64, 64><<<MG, 256, 0, stream>>>(in, ACC, W, bias, B0, accum, fin, V);
        else
            mix3_kernel<64, 10><<<MG, 256, 0, stream>>>(in, ACC, W, bias, B0, accum, fin, V);
    };
    auto stats_h = [&](const __half* xb, int C, int slot, const float* g, const float* be) {
        bn_stats_h_kernel<<<1024, 256, 0, stream>>>(xb, C, bn_sums + slot * 128, (size_t)V * 8 * C);
        bn_finalize_kernel<<<1, 64, 0, stream>>>(bn_sums + slot * 128, g, be, aff + slot * 128, C,
                                                 1.f / ((float)V * 8.f));
    };
    auto stats_f = [&](const float* xb, int C, int relu, int slot, const float* g, const float* be) {
        bn_stats_f_kernel<<<1024, 256, 0, stream>>>(xb, C, relu, bn_sums + slot * 128, (size_t)V * 8 * C);
        bn_finalize_kernel<<<1, 64, 0, stream>>>(bn_sums + slot * 128, g, be, aff + slot * 128, C,
                                                 1.f / ((float)V * 8.f));
    };
    auto affine_h = [&](__half* xb, int C, int slot) {
        affine_h_kernel<<<2048, 256, 0, stream>>>(xb, aff + slot * 128, C, (size_t)V * 8 * C);
    };
    auto affine_f2h = [&](const float* in, __half* out, int C, int slot) {
        affine_f2h_kernel<<<2048, 256, 0, stream>>>(in, out, aff + slot * 128, C, (size_t)V * 8 * C);
    };
    // K=4 Chebyshev conv of B0 (Cin ch) into ACC (Cout ch); last mix fin mode.
    auto cheb_a = [&](int Cin, int Cout, const float* W, const float* bias, int lastfin) {
        mix(B0, Cin, Cout, W, bias, 0, -1);                    // T0 = xn
        spmm(B0, B1, nullptr, Cin);                            // T1 = L xn
        mix(B1, Cin, Cout, W + 1 * Cin * Cout, nullptr, 1, -1);
        spmm(B1, B2, B0, Cin);                                 // T2 = 2 L T1 - xn
        mix(B2, Cin, Cout, W + 2 * Cin * Cout, nullptr, 1, -1);
        spmm(B2, B1, B1, Cin);                                 // T3 = 2 L T2 - T1
        mix(B1, Cin, Cout, W + 3 * Cin * Cout, nullptr, 1, lastfin);
    };
    // input y = B1, scratch B2; B0 preserved (= xn, residual source)
    auto cheb_b = [&](int C, const float* W, const float* bias, int lastfin) {
        mix(B1, C, C, W, bias, 0, -1);                         // T0 = y
        spmm(B1, B2, nullptr, C);                              // T1 = L y
        mix(B2, C, C, W + C * C, nullptr, 1, -1);
        spmm(B2, B1, B1, C);                                   // T2 = 2 L T1 - y
        mix(B1, C, C, W + 2 * C * C, nullptr, 1, -1);
        spmm(B1, B2, B2, C);                                   // T3 = 2 L T2 - T1
        mix(B2, C, C, W + 3 * C * C, nullptr, 1, lastfin);
    };

    // ---- conv_in: x(16ch) -> relu(cheb+b) -> B0 (32ch), fused finalize ----
    cheb_a(16, 32, W_in, b_in, 0);

    // ---- block 1: 32 -> 32, identity shortcut ----
    stats_h(B0, 32, 0, g1a, be1a);
    affine_h(B0, 32, 0);                     // B0 = xn
    cheb_a(32, 32, W1a, b1a, -1);            // ACC = out_a
    stats_f(ACC, 32, 1, 1, g1b, be1b);
    affine_f2h(ACC, B1, 32, 1);              // B1 = y = bn(relu(out_a))
    cheb_b(32, W1b, b1b, 1);                 // B0 = relu(conv_b(y) + xn)

    // ---- block 2: 32 -> 64, W2s shortcut ----
    stats_h(B0, 32, 2, g2a, be2a);
    affine_h(B0, 32, 2);                     // B0 = xn (32ch)
    cheb_a(32, 64, W2a, b2a, -1);            // ACC = out_a (64ch)
    stats_f(ACC, 64, 1, 3, g2b, be2b);
    affine_f2h(ACC, B1, 64, 3);              // B1 = y (64ch)
    // cheb_b(64) with W2s accumulated before the finalize mix:
    mix(B1, 64, 64, W2b, b2b, 0, -1);
    spmm(B1, B2, nullptr, 64);
    mix(B2, 64, 64, W2b + 1 * 64 * 64, nullptr, 1, -1);
    spmm(B2, B1, B1, 64);
    mix(B1, 64, 64, W2b + 2 * 64 * 64, nullptr, 1, -1);
    spmm(B1, B2, B2, 64);
    mix(B0, 32, 64, W2s, nullptr, 1, -1);    // ACC += xn @ W2s (B0 still 32ch xn)
    mix(B2, 64, 64, W2b + 3 * 64 * 64, nullptr, 1, 0);   // B0 = relu(ACC + T3 W3)

    // ---- block 3: 64 -> 64, identity shortcut ----
    stats_h(B0, 64, 4, g3a, be3a);
    affine_h(B0, 64, 4);                     // B0 = xn
    cheb_a(64, 64, W3a, b3a, -1);
    stats_f(ACC, 64, 1, 5, g3b, be3b);
    affine_f2h(ACC, B1, 64, 5);              // B1 = y
    cheb_b(64, W3b, b3b, 1);                 // B0 = relu(conv_b(y) + xn)

    // ---- head: bn -> cheb(64->10) -> relu(max-pool) -> log_softmax ----
    stats_h(B0, 64, 6, g_o, be_o);
    affine_h(B0, 64, 6);                     // B0 = bn(x)
    cheb_a(64, 10, W_o, b_o, -1);            // ACC = logits per node (80 wide)
    maxpool_kernel<<<80, 256, 0, stream>>>(ACC, pooled, V);   // implicit relu
    lsm_kernel<<<1, 64, 0, stream>>>(pooled, (float*)d_out);
}

// Round 10
// 4897.172 us; speedup vs baseline: 1.0403x; 1.0403x over previous
//
#include <hip/hip_runtime.h>
#include <hip/hip_bf16.h>
#include <hip/hip_fp16.h>

// ===========================================================================
// CSR build (multi-block scan; deterministic via per-row sort)
// ===========================================================================
__global__ void hist_kernel(const int* __restrict__ rows, int* __restrict__ counts, int E) {
    int i = blockIdx.x * blockDim.x + threadIdx.x;
    if (i < E) atomicAdd(&counts[rows[i]], 1);
}

__global__ void chunk_sum_kernel(const int* __restrict__ counts, int* __restrict__ chunk_sums, int V) {
    __shared__ int sh[256];
    int t = threadIdx.x;
    int i = blockIdx.x * 256 + t;
    sh[t] = (i < V) ? counts[i] : 0;
    __syncthreads();
    for (int st = 128; st > 0; st >>= 1) {
        if (t < st) sh[t] += sh[t + st];
        __syncthreads();
    }
    if (t == 0) chunk_sums[blockIdx.x] = sh[0];
}

__global__ void scan_chunks_kernel(int* __restrict__ cs, int n) {
    __shared__ int wsum[4];
    int t = threadIdx.x, lane = t & 63, w = t >> 6;
    int orig = (t < n) ? cs[t] : 0;
    int x = orig;
    #pragma unroll
    for (int d = 1; d < 64; d <<= 1) {
        int y = __shfl_up(x, d);
        if (lane >= d) x += y;
    }
    if (lane == 63) wsum[w] = x;
    __syncthreads();
    int wo = 0;
    for (int j = 0; j < w; ++j) wo += wsum[j];
    if (t < n) cs[t] = wo + x - orig;     // exclusive
}

__global__ void scan_final_kernel(const int* __restrict__ counts, const int* __restrict__ chunk_off,
                                  int* __restrict__ row_ptr, int V) {
    __shared__ int wsum[4];
    int t = threadIdx.x, lane = t & 63, w = t >> 6;
    int i = blockIdx.x * 256 + t;
    int x = (i < V) ? counts[i] : 0;
    #pragma unroll
    for (int d = 1; d < 64; d <<= 1) {
        int y = __shfl_up(x, d);
        if (lane >= d) x += y;
    }
    if (lane == 63) wsum[w] = x;
    __syncthreads();
    int wo = 0;
    for (int j = 0; j < w; ++j) wo += wsum[j];
    if (i < V) row_ptr[i + 1] = chunk_off[blockIdx.x] + wo + x;
    if (i == 0) row_ptr[0] = 0;
}

__global__ void init_cursor_kernel(const int* __restrict__ row_ptr, int* __restrict__ cursor, int V) {
    int i = blockIdx.x * blockDim.x + threadIdx.x;
    if (i < V) cursor[i] = row_ptr[i];
}

__global__ void scatter_kernel(const int* __restrict__ rows, const int* __restrict__ cols,
                               const float* __restrict__ vals, int* __restrict__ cursor,
                               int* __restrict__ cols_s, float* __restrict__ vals_s, int E) {
    int i = blockIdx.x * blockDim.x + threadIdx.x;
    if (i < E) {
        int r = rows[i];
        int p = atomicAdd(&cursor[r], 1);
        cols_s[p] = cols[i];
        vals_s[p] = vals[i];
    }
}

// canonical per-row order: insertion sort by (col, val-bits). Makes CSR
// bitwise-deterministic regardless of scatter's atomic ordering.
__global__ void sort_rows_kernel(const int* __restrict__ row_ptr, int* cols, float* vals, int V) {
    int v = blockIdx.x * blockDim.x + threadIdx.x;
    if (v >= V) return;
    int e0 = row_ptr[v], e1 = row_ptr[v + 1];
    for (int i = e0 + 1; i < e1; ++i) {
        int c = cols[i];
        unsigned xb = __float_as_uint(vals[i]);
        int j = i - 1;
        while (j >= e0) {
            int cj = cols[j];
            unsigned vj = __float_as_uint(vals[j]);
            if (cj > c || (cj == c && vj > xb)) {
                cols[j + 1] = cj; vals[j + 1] = __uint_as_float(vj);
                --j;
            } else break;
        }
        cols[j + 1] = c;
        vals[j + 1] = __uint_as_float(xb);
    }
}

// ===========================================================================
// transpose input (B,16,V) fp32 -> (V, B*16) fp16
// ===========================================================================
__global__ void transpose_in_kernel(const float* __restrict__ x, __half* __restrict__ X, int V) {
    int total = V * 128;
    for (int i = blockIdx.x * blockDim.x + threadIdx.x; i < total; i += gridDim.x * blockDim.x) {
        int v = i >> 7;
        int t = i & 127;          // t = b*16 + c
        X[i] = __float2half(x[t * V + v]);
    }
}

// ===========================================================================
// SpMM: one wave per node, lane owns VPT half2, unroll 8.
//   dst[v,:] = sum_e vals[e]*src[cols[e],:]        (prev == null)
//   dst[v,:] = 2*that - prev[v,:]                  (prev != null)
// dst always distinct from src/prev in the schedule.
// ===========================================================================
template <int VPT> struct PackT;
template <> struct PackT<1> { using T = float;  };
template <> struct PackT<2> { using T = float2; };
template <> struct PackT<4> { using T = float4; };

template <int VPT>
__global__ __launch_bounds__(256) void spmm2_kernel(
    const int* __restrict__ row_ptr, const int* __restrict__ cols,
    const float* __restrict__ vals, const __half2* __restrict__ src,
    __half2* dst, const __half2* prev, int V) {
    using T = typename PackT<VPT>::T;
    union U { T raw; __half2 h[VPT]; };
    int lane = threadIdx.x & 63;
    int v = (blockIdx.x << 2) | (threadIdx.x >> 6);
    if (v >= V) return;
    const int W = VPT * 64;
    const size_t row = (size_t)v * W + lane * VPT;

    float pr[2 * VPT];
    bool hasp = (prev != nullptr);
    if (hasp) {
        U pv; pv.raw = *(const T*)(prev + row);
        #pragma unroll
        for (int j = 0; j < VPT; ++j) {
            float2 f = __half22float2(pv.h[j]);
            pr[2 * j] = f.x; pr[2 * j + 1] = f.y;
        }
    }
    float acc[2 * VPT];
    #pragma unroll
    for (int j = 0; j < 2 * VPT; ++j) acc[j] = 0.f;

    int e0 = row_ptr[v], e1 = row_ptr[v + 1];
    int e = e0;
    for (; e + 8 <= e1; e += 8) {
        int   c[8]; float w[8]; U g[8];
        #pragma unroll
        for (int k = 0; k < 8; ++k) { c[k] = cols[e + k]; w[k] = vals[e + k]; }
        #pragma unroll
        for (int k = 0; k < 8; ++k)
            g[k].raw = *(const T*)(src + (size_t)c[k] * W + lane * VPT);
        #pragma unroll
        for (int k = 0; k < 8; ++k) {
            #pragma unroll
            for (int j = 0; j < VPT; ++j) {
                float2 f = __half22float2(g[k].h[j]);
                acc[2*j] += w[k] * f.x; acc[2*j+1] += w[k] * f.y;
            }
        }
    }
    for (; e + 4 <= e1; e += 4) {
        int   c[4]; float w[4]; U g[4];
        #pragma unroll
        for (int k = 0; k < 4; ++k) { c[k] = cols[e + k]; w[k] = vals[e + k]; }
        #pragma unroll
        for (int k = 0; k < 4; ++k)
            g[k].raw = *(const T*)(src + (size_t)c[k] * W + lane * VPT);
        #pragma unroll
        for (int k = 0; k < 4; ++k) {
            #pragma unroll
            for (int j = 0; j < VPT; ++j) {
                float2 f = __half22float2(g[k].h[j]);
                acc[2*j] += w[k] * f.x; acc[2*j+1] += w[k] * f.y;
            }
        }
    }
    for (; e < e1; ++e) {
        int c = cols[e]; float wv = vals[e];
        U g; g.raw = *(const T*)(src + (size_t)c * W + lane * VPT);
        #pragma unroll
        for (int j = 0; j < VPT; ++j) {
            float2 f = __half22float2(g.h[j]);
            acc[2*j] += wv * f.x; acc[2*j+1] += wv * f.y;
        }
    }
    if (hasp) {
        #pragma unroll
        for (int j = 0; j < 2 * VPT; ++j) acc[j] = 2.f * acc[j] - pr[j];
    }
    U o;
    #pragma unroll
    for (int j = 0; j < VPT; ++j) o.h[j] = __floats2half2_rn(acc[2*j], acc[2*j+1]);
    *(T*)(dst + row) = o.raw;
}

// ===========================================================================
// combine: out = f( sum_k T_k @ W_k + bias [+ res] [+ sc @ Wsc] )
// Thread = (node, batch), COUT fp32 accs in VGPRs, W via SGPR broadcast.
// NOTE: T*/res/sc/out intentionally NOT __restrict__ — out may alias an
// input buffer; each thread reads/writes only its own (node,batch) slice,
// reads before writes in program order, so aliasing is well-defined.
// ===========================================================================
template <int CIN, int COUT>
__global__ __launch_bounds__(256) void combine_kernel(
    const __half* T0, const __half* T1, const __half* T2, const __half* T3,
    const float* __restrict__ W, const float* __restrict__ bias,
    const __half* res, const __half* sc, const float* __restrict__ Wsc,
    __half* out, int relu, int V) {
    const int CSC = 32;
    int g = blockIdx.x * 256 + threadIdx.x;
    int n = g >> 3, b = g & 7;
    if (n >= V) return;
    size_t ib = (size_t)n * 8 * CIN + (size_t)b * CIN;

    float acc[COUT];
    if (bias) {
        #pragma unroll
        for (int c = 0; c < COUT; ++c) acc[c] = bias[c];
    } else {
        #pragma unroll
        for (int c = 0; c < COUT; ++c) acc[c] = 0.f;
    }

    const __half* Ts[4] = {T0, T1, T2, T3};
    #pragma unroll
    for (int k = 0; k < 4; ++k) {
        const __half2* xr = (const __half2*)(Ts[k] + ib);
        const float* Wk = W + (size_t)k * CIN * COUT;
        for (int q = 0; q < CIN / 2; ++q) {
            float2 x = __half22float2(xr[q]);
            const float* w0 = Wk + (2 * q) * COUT;
            const float* w1 = Wk + (2 * q + 1) * COUT;
            #pragma unroll
            for (int c = 0; c < COUT; ++c) acc[c] = fmaf(x.x, w0[c], acc[c]);
            #pragma unroll
            for (int c = 0; c < COUT; ++c) acc[c] = fmaf(x.y, w1[c], acc[c]);
        }
    }
    if (sc) {
        const __half2* xr = (const __half2*)(sc + (size_t)n * 8 * CSC + (size_t)b * CSC);
        for (int q = 0; q < CSC / 2; ++q) {
            float2 x = __half22float2(xr[q]);
            const float* w0 = Wsc + (2 * q) * COUT;
            const float* w1 = Wsc + (2 * q + 1) * COUT;
            #pragma unroll
            for (int c = 0; c < COUT; ++c) acc[c] = fmaf(x.x, w0[c], acc[c]);
            #pragma unroll
            for (int c = 0; c < COUT; ++c) acc[c] = fmaf(x.y, w1[c], acc[c]);
        }
    }
    size_t ob = (size_t)n * 8 * COUT + (size_t)b * COUT;
    if (res) {
        const __half2* rr = (const __half2*)(res + ob);
        #pragma unroll
        for (int c = 0; c < COUT / 2; ++c) {
            float2 f = __half22float2(rr[c]);
            acc[2 * c] += f.x; acc[2 * c + 1] += f.y;
        }
    }
    if (relu) {
        #pragma unroll
        for (int c = 0; c < COUT; ++c) acc[c] = fmaxf(acc[c], 0.f);
    }
    __half2* ro = (__half2*)(out + ob);
    #pragma unroll
    for (int c = 0; c < COUT / 2; ++c)
        ro[c] = __floats2half2_rn(acc[2 * c], acc[2 * c + 1]);
}

// ===========================================================================
// BatchNorm: two-stage deterministic stats (no float atomics)
// stage 1: per-block partials -> part[blk*128 + {c, C+c}]
// stage 2: ordered reduce over blocks + finalize to scale/shift
// ===========================================================================
__global__ void bn_stats_part_kernel(const __half* __restrict__ x, int C, int relu_in,
                                     float* __restrict__ part, size_t N) {
    __shared__ float s_sum[256];
    __shared__ float s_sq[256];
    int t = threadIdx.x;
    size_t i0 = (size_t)blockIdx.x * 256 + t;
    size_t step = (size_t)gridDim.x * 256;
    float s = 0.f, q = 0.f;
    for (size_t i = i0; i < N; i += step) {
        float v = __half2float(x[i]);
        if (relu_in) v = fmaxf(v, 0.f);
        s += v; q += v * v;
    }
    s_sum[t] = s; s_sq[t] = q;
    __syncthreads();
    for (int st = 128; st >= C; st >>= 1) {
        if (t < st) { s_sum[t] += s_sum[t + st]; s_sq[t] += s_sq[t + st]; }
        __syncthreads();
    }
    if (t < C) {
        part[blockIdx.x * 128 + t]     = s_sum[t];
        part[blockIdx.x * 128 + C + t] = s_sq[t];
    }
}

__global__ void bn_reduce_kernel(const float* __restrict__ part, int nblk,
                                 const float* __restrict__ g, const float* __restrict__ be,
                                 float* __restrict__ ss, int C, float invN) {
    int c = threadIdx.x;
    if (c < C) {
        float s = 0.f, q = 0.f;
        for (int b = 0; b < nblk; ++b) {        // fixed order -> deterministic
            s += part[b * 128 + c];
            q += part[b * 128 + C + c];
        }
        float m = s * invN;
        float var = q * invN - m * m;
        float sc = g[c] * rsqrtf(var + 1e-5f);
        ss[c] = sc;
        ss[C + c] = be[c] - m * sc;
    }
}

// in-place: x = f(x)*a + b, f = relu if relu_in
__global__ void affine_h_kernel(__half* x, const float* __restrict__ ss, int C,
                                int relu_in, size_t N) {
    size_t stride = (size_t)gridDim.x * blockDim.x;
    for (size_t i = (size_t)blockIdx.x * blockDim.x + threadIdx.x; i < N; i += stride) {
        int c = (int)(i & (size_t)(C - 1));
        float v = __half2float(x[i]);
        if (relu_in) v = fmaxf(v, 0.f);
        x[i] = __float2half(v * ss[c] + ss[C + c]);
    }
}

// ===========================================================================
// head: max over nodes (inputs post-relu >= 0) + log_softmax (fp32 out)
// ===========================================================================
__global__ void maxpool_h_kernel(const __half* __restrict__ x, float* __restrict__ pooled, int V) {
    __shared__ float red[256];
    int o = blockIdx.x;     // 0..79 (b*10+co)
    float m = 0.f;
    for (int v = threadIdx.x; v < V; v += 256)
        m = fmaxf(m, __half2float(x[(size_t)v * 80 + o]));
    red[threadIdx.x] = m;
    __syncthreads();
    for (int st = 128; st > 0; st >>= 1) {
        if (threadIdx.x < st) red[threadIdx.x] = fmaxf(red[threadIdx.x], red[threadIdx.x + st]);
        __syncthreads();
    }
    if (threadIdx.x == 0) pooled[o] = red[0];
}

__global__ void lsm_kernel(const float* __restrict__ pooled, float* __restrict__ out) {
    int b = threadIdx.x;
    if (b < 8) {
        float m = -1e30f;
        for (int c = 0; c < 10; ++c) m = fmaxf(m, pooled[b * 10 + c]);
        float s = 0.f;
        for (int c = 0; c < 10; ++c) s += expf(pooled[b * 10 + c] - m);
        float l = logf(s);
        for (int c = 0; c < 10; ++c)
            out[b * 10 + c] = pooled[b * 10 + c] - m - l;
    }
}

__global__ void encode_kernel(float* out, float val) {
    int i = threadIdx.x;
    if (i < 80) out[i] = val;
}

// ===========================================================================
// entry
// ===========================================================================
extern "C" void kernel_launch(void* const* d_in, const int* in_sizes, int n_in,
                              void* d_out, int out_size, void* d_ws, size_t ws_size,
                              hipStream_t stream) {
    (void)in_sizes; (void)n_in; (void)out_size;
    const int V = 50000, E = 800000;
    const int NCH = (V + 255) / 256;
    const int SB = 256;                       // bn stage-1 blocks

    auto al = [](size_t x) { return (x + 255) & ~(size_t)255; };
    const size_t FB = al((size_t)V * 512 * sizeof(__half));     // 51.2 MB
    const size_t need = 5 * FB + al((V + 1) * 4) + al(V * 4) + al(E * 4) + al(E * 4)
                      + al(SB * 128 * 4) + al(8 * 128 * 4) + al(80 * 4) + al(NCH * 4);
    if (ws_size < need) {
        encode_kernel<<<1, 128, 0, stream>>>((float*)d_out, (float)(ws_size >> 20));
        return;
    }

    const float* x_in = (const float*)d_in[0];
    const int* rows   = (const int*)d_in[1];
    const int* colsi  = (const int*)d_in[2];
    const float* lvals = (const float*)d_in[3];
    const float* W_in = (const float*)d_in[4];
    const float* b_in = (const float*)d_in[5];
    const float* g1a = (const float*)d_in[6],  *be1a = (const float*)d_in[7];
    const float* W1a = (const float*)d_in[8],  *b1a  = (const float*)d_in[9];
    const float* g1b = (const float*)d_in[10], *be1b = (const float*)d_in[11];
    const float* W1b = (const float*)d_in[12], *b1b  = (const float*)d_in[13];
    const float* g2a = (const float*)d_in[14], *be2a = (const float*)d_in[15];
    const float* W2a = (const float*)d_in[16], *b2a  = (const float*)d_in[17];
    const float* g2b = (const float*)d_in[18], *be2b = (const float*)d_in[19];
    const float* W2b = (const float*)d_in[20], *b2b  = (const float*)d_in[21];
    const float* W2s = (const float*)d_in[22];
    const float* g3a = (const float*)d_in[23], *be3a = (const float*)d_in[24];
    const float* W3a = (const float*)d_in[25], *b3a  = (const float*)d_in[26];
    const float* g3b = (const float*)d_in[27], *be3b = (const float*)d_in[28];
    const float* W3b = (const float*)d_in[29], *b3b  = (const float*)d_in[30];
    const float* g_o = (const float*)d_in[31], *be_o = (const float*)d_in[32];
    const float* W_o = (const float*)d_in[33], *b_o  = (const float*)d_in[34];

    char* wp = (char*)d_ws;
    auto take = [&](size_t bytes) -> void* { void* p = (void*)wp; wp += al(bytes); return p; };
    __half* P0 = (__half*)take(FB);
    __half* P1 = (__half*)take(FB);
    __half* P2 = (__half*)take(FB);
    __half* P3 = (__half*)take(FB);
    __half* P4 = (__half*)take(FB);
    int* row_ptr  = (int*)take((V + 1) * sizeof(int));
    int* cursor   = (int*)take(V * sizeof(int));
    int* cols_s   = (int*)take(E * sizeof(int));
    float* vals_s = (float*)take(E * sizeof(float));
    float* part   = (float*)take(SB * 128 * sizeof(float));
    float* aff    = (float*)take(8 * 128 * sizeof(float));
    float* pooled = (float*)take(80 * sizeof(float));
    int* chunks   = (int*)take(NCH * sizeof(int));

    // ---- determinism: identical ws state at the start of EVERY launch ----
    hipMemsetAsync(d_ws, 0, need, stream);

    // ---- CSR build (+canonical row order) + input transpose ----
    hist_kernel<<<(E + 255) / 256, 256, 0, stream>>>(rows, cursor, E);
    chunk_sum_kernel<<<NCH, 256, 0, stream>>>(cursor, chunks, V);
    scan_chunks_kernel<<<1, 256, 0, stream>>>(chunks, NCH);
    scan_final_kernel<<<NCH, 256, 0, stream>>>(cursor, chunks, row_ptr, V);
    init_cursor_kernel<<<(V + 255) / 256, 256, 0, stream>>>(row_ptr, cursor, V);
    scatter_kernel<<<(E + 255) / 256, 256, 0, stream>>>(rows, colsi, lvals, cursor, cols_s, vals_s, E);
    sort_rows_kernel<<<(V + 255) / 256, 256, 0, stream>>>(row_ptr, cols_s, vals_s, V);
    transpose_in_kernel<<<4096, 256, 0, stream>>>(x_in, P0, V);

    // ---- helpers ----
    auto spmm = [&](const __half* src, __half* dst, const __half* prev, int C) {
        int grid = (V + 3) / 4;
        if (C == 16)
            spmm2_kernel<1><<<grid, 256, 0, stream>>>(row_ptr, cols_s, vals_s,
                (const __half2*)src, (__half2*)dst, (const __half2*)prev, V);
        else if (C == 32)
            spmm2_kernel<2><<<grid, 256, 0, stream>>>(row_ptr, cols_s, vals_s,
                (const __half2*)src, (__half2*)dst, (const __half2*)prev, V);
        else
            spmm2_kernel<4><<<grid, 256, 0, stream>>>(row_ptr, cols_s, vals_s,
                (const __half2*)src, (__half2*)dst, (const __half2*)prev, V);
    };
    const int MG = (V * 8 + 255) / 256;
    auto comb = [&](const __half* T0, const __half* T1, const __half* T2, const __half* T3,
                    int Cin, int Cout, const float* W, const float* bias,
                    const __half* res, const __half* sc, const float* Wsc,
                    __half* out, int relu) {
        if (Cin == 16 && Cout == 32)
            combine_kernel<16, 32><<<MG, 256, 0, stream>>>(T0, T1, T2, T3, W, bias, res, sc, Wsc, out, relu, V);
        else if (Cin == 32 && Cout == 32)
            combine_kernel<32, 32><<<MG, 256, 0, stream>>>(T0, T1, T2, T3, W, bias, res, sc, Wsc, out, relu, V);
        else if (Cin == 32 && Cout == 64)
            combine_kernel<32, 64><<<MG, 256, 0, stream>>>(T0, T1, T2, T3, W, bias, res, sc, Wsc, out, relu, V);
        else if (Cin == 64 && Cout == 64)
            combine_kernel<64, 64><<<MG, 256, 0, stream>>>(T0, T1, T2, T3, W, bias, res, sc, Wsc, out, relu, V);
        else
            combine_kernel<64, 10><<<MG, 256, 0, stream>>>(T0, T1, T2, T3, W, bias, res, sc, Wsc, out, relu, V);
    };
    auto stats = [&](const __half* xb, int C, int relu, int slot, const float* g, const float* be) {
        bn_stats_part_kernel<<<SB, 256, 0, stream>>>(xb, C, relu, part, (size_t)V * 8 * C);
        bn_reduce_kernel<<<1, 64, 0, stream>>>(part, SB, g, be, aff + slot * 128, C,
                                               1.f / ((float)V * 8.f));
    };
    auto affine = [&](__half* xb, int C, int relu, int slot) {
        affine_h_kernel<<<2048, 256, 0, stream>>>(xb, aff + slot * 128, C, relu, (size_t)V * 8 * C);
    };
    const __half* NH = nullptr;
    const float*  NF = nullptr;

    // ---- conv_in: x=P0 (16ch) -> relu(cheb+b) -> P4 (32ch) ----
    spmm(P0, P1, nullptr, 16);              // T1
    spmm(P1, P2, P0, 16);                   // T2
    spmm(P2, P3, P1, 16);                   // T3
    comb(P0, P1, P2, P3, 16, 32, W_in, b_in, NH, NH, NF, P4, 1);

    // ---- block 1 (X=P4, 32ch, identity shortcut) ----
    stats(P4, 32, 0, 0, g1a, be1a);
    affine(P4, 32, 0, 0);                   // P4 = xn
    spmm(P4, P0, nullptr, 32);
    spmm(P0, P1, P4, 32);
    spmm(P1, P2, P0, 32);
    comb(P4, P0, P1, P2, 32, 32, W1a, b1a, NH, NH, NF, P0, 0);   // out_a = P0
    stats(P0, 32, 1, 1, g1b, be1b);
    affine(P0, 32, 1, 1);                   // P0 = y
    spmm(P0, P1, nullptr, 32);
    spmm(P1, P2, P0, 32);
    spmm(P2, P3, P1, 32);
    comb(P0, P1, P2, P3, 32, 32, W1b, b1b, P4, NH, NF, P4, 1);   // P4 = block1 out

    // ---- block 2 (X=P4, 32ch -> 64ch, W2s shortcut) ----
    stats(P4, 32, 0, 2, g2a, be2a);
    affine(P4, 32, 0, 2);                   // P4 = xn (32ch)
    spmm(P4, P0, nullptr, 32);
    spmm(P0, P1, P4, 32);
    spmm(P1, P2, P0, 32);
    comb(P4, P0, P1, P2, 32, 64, W2a, b2a, NH, NH, NF, P3, 0);   // out_a = P3 (64ch)
    stats(P3, 64, 1, 3, g2b, be2b);
    affine(P3, 64, 1, 3);                   // P3 = y
    spmm(P3, P0, nullptr, 64);
    spmm(P0, P1, P3, 64);
    spmm(P1, P2, P0, 64);
    comb(P3, P0, P1, P2, 64, 64, W2b, b2b, NH, P4, W2s, P0, 1);  // P0 = block2 out

    // ---- block 3 (X=P0, 64ch, identity shortcut) ----
    stats(P0, 64, 0, 4, g3a, be3a);
    affine(P0, 64, 0, 4);                   // P0 = xn
    spmm(P0, P1, nullptr, 64);
    spmm(P1, P2, P0, 64);
    spmm(P2, P3, P1, 64);
    comb(P0, P1, P2, P3, 64, 64, W3a, b3a, NH, NH, NF, P1, 0);   // out_a = P1
    stats(P1, 64, 1, 5, g3b, be3b);
    affine(P1, 64, 1, 5);                   // P1 = y
    spmm(P1, P2, nullptr, 64);
    spmm(P2, P3, P1, 64);
    spmm(P3, P4, P2, 64);
    comb(P1, P2, P3, P4, 64, 64, W3b, b3b, P0, NH, NF, P1, 1);   // P1 = block3 out

    // ---- head: bn -> relu(cheb 64->10) -> maxpool -> log_softmax ----
    stats(P1, 64, 0, 6, g_o, be_o);
    affine(P1, 64, 0, 6);                   // P1 = bn(x)
    spmm(P1, P0, nullptr, 64);
    spmm(P0, P2, P1, 64);
    spmm(P2, P3, P0, 64);
    comb(P1, P0, P2, P3, 64, 10, W_o, b_o, NH, NH, NF, P4, 1);   // P4 = 80-wide logits
    maxpool_h_kernel<<<80, 256, 0, stream>>>(P4, pooled, V);
    lsm_kernel<<<1, 64, 0, stream>>>(pooled, (float*)d_out);
}